// Round 1
// baseline (607.244 us; speedup 1.0000x reference)
//
#include <hip/hip_runtime.h>
#include <math.h>

#define NVERT 6890
#define NBATCH 1024
#define V3 20670        // NVERT*3
#define BT 8            // batches per block in vertex kernel

// workspace layout (float offsets)
#define WS_SJ 0                        // 10*72 = 720   SJ[k][j][c]
#define WS_JT 720                      // 72            JT[j][c]
#define WS_A  1024                     // NBATCH*384    A'[b][j][r][c] (adjusted)
#define WS_PF (1024 + NBATCH*384)      // NBATCH*207    pose_feature

// ---------------------------------------------------------------------------
// K0: SJ[k][j][c] = sum_v shapedirs[k][v*3+c] * J_regressor[v][j]
//     JT[j][c]    = sum_v v_template[v][c]    * J_regressor[v][j]
// grid: 72 blocks (j*3+c), 256 threads
// ---------------------------------------------------------------------------
__global__ __launch_bounds__(256) void k0_joint_reduce(
    const float* __restrict__ v_template,
    const float* __restrict__ shapedirs,
    const float* __restrict__ J_regressor,
    float* ws)
{
    int j = blockIdx.x / 3;
    int c = blockIdx.x % 3;
    int t = threadIdx.x;

    float acc[11];
#pragma unroll
    for (int i = 0; i < 11; ++i) acc[i] = 0.f;

    for (int v = t; v < NVERT; v += 256) {
        float jr = J_regressor[v * 24 + j];
        acc[10] = fmaf(v_template[v * 3 + c], jr, acc[10]);
#pragma unroll
        for (int k = 0; k < 10; ++k)
            acc[k] = fmaf(shapedirs[k * V3 + v * 3 + c], jr, acc[k]);
    }

    __shared__ float red[256];
    for (int i = 0; i < 11; ++i) {
        red[t] = acc[i];
        __syncthreads();
        for (int s = 128; s > 0; s >>= 1) {
            if (t < s) red[t] += red[t + s];
            __syncthreads();
        }
        if (t == 0) {
            if (i < 10) ws[WS_SJ + i * 72 + j * 3 + c] = red[0];
            else        ws[WS_JT + j * 3 + c]          = red[0];
        }
        __syncthreads();
    }
}

// ---------------------------------------------------------------------------
// K1: per-batch Rodrigues + J + pose_feature + kinematic chain -> A' (24x16)
// grid: NBATCH blocks, 64 threads (1 wave)
// ---------------------------------------------------------------------------
__global__ __launch_bounds__(64) void k1_pose(
    const float* __restrict__ theta,
    const float* __restrict__ beta,
    float* ws)
{
    int b = blockIdx.x;
    int t = threadIdx.x;

    __shared__ float Rs[24][9];
    __shared__ float Jl[24][3];
    __shared__ float res[24][16];
    __shared__ float Ai[16];

    if (t < 24) {
        float tx = theta[b * 72 + t * 3 + 0];
        float ty = theta[b * 72 + t * 3 + 1];
        float tz = theta[b * 72 + t * 3 + 2];
        float ax = tx + 1e-8f, ay = ty + 1e-8f, az = tz + 1e-8f;
        float ang = sqrtf(ax * ax + ay * ay + az * az);
        float h = 0.5f * ang;
        float cw = cosf(h), sw = sinf(h);
        float qw = cw;
        float qx = sw * (tx / ang);
        float qy = sw * (ty / ang);
        float qz = sw * (tz / ang);
        float qn = sqrtf(qw * qw + qx * qx + qy * qy + qz * qz);
        qw /= qn; qx /= qn; qy /= qn; qz /= qn;
        float w2 = qw * qw, x2 = qx * qx, y2 = qy * qy, z2 = qz * qz;
        float wx = qw * qx, wy = qw * qy, wz = qw * qz;
        float xy = qx * qy, xz = qx * qz, yz = qy * qz;
        Rs[t][0] = w2 + x2 - y2 - z2;
        Rs[t][1] = 2.f * xy - 2.f * wz;
        Rs[t][2] = 2.f * wy + 2.f * xz;
        Rs[t][3] = 2.f * wz + 2.f * xy;
        Rs[t][4] = w2 - x2 + y2 - z2;
        Rs[t][5] = 2.f * yz - 2.f * wx;
        Rs[t][6] = 2.f * xz - 2.f * wy;
        Rs[t][7] = 2.f * wx + 2.f * yz;
        Rs[t][8] = w2 - x2 - y2 + z2;
    }
    __syncthreads();

    // J[j][c] = sum_k beta[k]*SJ[k][j][c] + JT[j][c]
    for (int i = t; i < 72; i += 64) {
        float s = ws[WS_JT + i];
#pragma unroll
        for (int k = 0; k < 10; ++k)
            s = fmaf(beta[b * 10 + k], ws[WS_SJ + k * 72 + i], s);
        Jl[i / 3][i % 3] = s;
    }

    // pose_feature = (Rs[1:] - I).flatten()
    for (int i = t; i < 207; i += 64) {
        int j = 1 + i / 9, e = i % 9;
        float sub = (e == 0 || e == 4 || e == 8) ? 1.f : 0.f;
        ws[WS_PF + b * 207 + i] = Rs[j][e] - sub;
    }
    __syncthreads();

    // kinematic chain
    if (t < 16) {
        int r = t >> 2, c = t & 3;
        res[0][t] = (r < 3) ? (c < 3 ? Rs[0][r * 3 + c] : Jl[0][r])
                            : (c == 3 ? 1.f : 0.f);
    }
    __syncthreads();

    const int PAR[24] = {-1,0,0,0,1,2,3,4,5,6,7,8,9,9,9,12,13,14,16,17,18,19,20,21};
    for (int i = 1; i < 24; ++i) {
        int p = PAR[i];
        if (t < 16) {
            int r = t >> 2, c = t & 3;
            Ai[t] = (r < 3) ? (c < 3 ? Rs[i][r * 3 + c] : (Jl[i][r] - Jl[p][r]))
                            : (c == 3 ? 1.f : 0.f);
        }
        __syncthreads();
        if (t < 16) {
            int r = t >> 2, c = t & 3;
            float s = 0.f;
#pragma unroll
            for (int k = 0; k < 4; ++k)
                s = fmaf(res[p][r * 4 + k], Ai[k * 4 + c], s);
            res[i][t] = s;
        }
        __syncthreads();
    }

    // A'[j][r][3] -= sum_{c<3} res[j][r][c]*J[j][c]; write out
    for (int i = t; i < 384; i += 64) {
        int j = i >> 4, rc = i & 15, r = rc >> 2, cc = rc & 3;
        float val = res[j][rc];
        if (cc == 3 && r < 3) {
            val -= res[j][r * 4 + 0] * Jl[j][0]
                 + res[j][r * 4 + 1] * Jl[j][1]
                 + res[j][r * 4 + 2] * Jl[j][2];
        }
        ws[WS_A + b * 384 + i] = val;
    }
}

// ---------------------------------------------------------------------------
// K2: vertex kernel, BT batches per block, 1 vertex per thread
// grid: (ceil(V/256)=27, NBATCH/BT=128), 256 threads
// ---------------------------------------------------------------------------
__global__ __launch_bounds__(256) void k2_vertex(
    const float* __restrict__ beta,
    const float* __restrict__ v_template,
    const float* __restrict__ shapedirs,
    const float* __restrict__ posedirs,
    const float* __restrict__ weights,
    const float* __restrict__ ws,
    float* __restrict__ out)
{
    int t  = threadIdx.x;
    int vb = blockIdx.x;
    int bg = blockIdx.y;
    int v  = vb * 256 + t;
    bool valid = v < NVERT;

    __shared__ float  pf_s[BT][207];
    __shared__ float  beta_s[BT][10];
    __shared__ float4 A_s[BT][96];     // 24 joints * 4 rows (float4)

    for (int i = t; i < BT * 207; i += 256) {
        int bt = i / 207, k = i - bt * 207;
        pf_s[bt][k] = ws[WS_PF + (bg * BT + bt) * 207 + k];
    }
    for (int i = t; i < BT * 10; i += 256) {
        int bt = i / 10, k = i - bt * 10;
        beta_s[bt][k] = beta[(bg * BT + bt) * 10 + k];
    }
    {
        const float4* Ag = (const float4*)(ws + WS_A);
        for (int i = t; i < BT * 96; i += 256) {
            int bt = i / 96, k = i - bt * 96;
            A_s[bt][k] = Ag[(bg * BT + bt) * 96 + k];
        }
    }
    __syncthreads();

    float vt0 = 0.f, vt1 = 0.f, vt2 = 0.f;
    if (valid) {
        vt0 = v_template[v * 3 + 0];
        vt1 = v_template[v * 3 + 1];
        vt2 = v_template[v * 3 + 2];
    }
    float acc0[BT], acc1[BT], acc2[BT];
#pragma unroll
    for (int bt = 0; bt < BT; ++bt) { acc0[bt] = vt0; acc1[bt] = vt1; acc2[bt] = vt2; }

    // shapedirs contribution (K=10)
#pragma unroll 2
    for (int k = 0; k < 10; ++k) {
        float s0 = 0.f, s1 = 0.f, s2 = 0.f;
        if (valid) {
            const float* p = shapedirs + k * V3 + v * 3;
            s0 = p[0]; s1 = p[1]; s2 = p[2];
        }
#pragma unroll
        for (int bt = 0; bt < BT; ++bt) {
            float f = beta_s[bt][k];
            acc0[bt] = fmaf(f, s0, acc0[bt]);
            acc1[bt] = fmaf(f, s1, acc1[bt]);
            acc2[bt] = fmaf(f, s2, acc2[bt]);
        }
    }

    // posedirs contribution (K=207) — the dominant matmul
#pragma unroll 4
    for (int k = 0; k < 207; ++k) {
        float s0 = 0.f, s1 = 0.f, s2 = 0.f;
        if (valid) {
            const float* p = posedirs + k * V3 + v * 3;
            s0 = p[0]; s1 = p[1]; s2 = p[2];
        }
#pragma unroll
        for (int bt = 0; bt < BT; ++bt) {
            float f = pf_s[bt][k];
            acc0[bt] = fmaf(f, s0, acc0[bt]);
            acc1[bt] = fmaf(f, s1, acc1[bt]);
            acc2[bt] = fmaf(f, s2, acc2[bt]);
        }
    }

    // skinning weights
    float w[24];
    if (valid) {
#pragma unroll
        for (int j = 0; j < 24; ++j) w[j] = weights[v * 24 + j];
    } else {
#pragma unroll
        for (int j = 0; j < 24; ++j) w[j] = 0.f;
    }

    // per-batch skinning + transform
#pragma unroll
    for (int bt = 0; bt < BT; ++bt) {
        float x = acc0[bt], y = acc1[bt], z = acc2[bt];
        float o0 = 0.f, o1 = 0.f, o2 = 0.f;
#pragma unroll
        for (int j = 0; j < 24; ++j) {
            float wj = w[j];
            float4 r0 = A_s[bt][j * 4 + 0];
            float4 r1 = A_s[bt][j * 4 + 1];
            float4 r2 = A_s[bt][j * 4 + 2];
            o0 = fmaf(wj, fmaf(r0.x, x, fmaf(r0.y, y, fmaf(r0.z, z, r0.w))), o0);
            o1 = fmaf(wj, fmaf(r1.x, x, fmaf(r1.y, y, fmaf(r1.z, z, r1.w))), o1);
            o2 = fmaf(wj, fmaf(r2.x, x, fmaf(r2.y, y, fmaf(r2.z, z, r2.w))), o2);
        }
        if (valid) {
            int b = bg * BT + bt;
            float* po = out + (size_t)b * V3 + v * 3;
            po[0] = o0; po[1] = o1; po[2] = o2;
        }
    }
}

extern "C" void kernel_launch(void* const* d_in, const int* in_sizes, int n_in,
                              void* d_out, int out_size, void* d_ws, size_t ws_size,
                              hipStream_t stream) {
    const float* theta       = (const float*)d_in[0];
    const float* beta        = (const float*)d_in[1];
    const float* v_template  = (const float*)d_in[2];
    const float* shapedirs   = (const float*)d_in[3];
    const float* posedirs    = (const float*)d_in[4];
    const float* J_regressor = (const float*)d_in[5];
    const float* weights     = (const float*)d_in[6];
    float* out = (float*)d_out;
    float* ws  = (float*)d_ws;

    hipLaunchKernelGGL(k0_joint_reduce, dim3(72), dim3(256), 0, stream,
                       v_template, shapedirs, J_regressor, ws);
    hipLaunchKernelGGL(k1_pose, dim3(NBATCH), dim3(64), 0, stream,
                       theta, beta, ws);
    hipLaunchKernelGGL(k2_vertex, dim3((NVERT + 255) / 256, NBATCH / BT), dim3(256), 0, stream,
                       beta, v_template, shapedirs, posedirs, weights, ws, out);
}

// Round 2
// 526.513 us; speedup vs baseline: 1.1533x; 1.1533x over previous
//
#include <hip/hip_runtime.h>
#include <math.h>

#define NVERT 6890
#define NBATCH 1024
#define V3 20670        // NVERT*3
#define BT 16           // batches per block in vertex kernel
#define NSLICE 8
#define SLICE_V 864     // 8*864 = 6912 >= 6890

// workspace layout (float offsets)
#define WS_SJP 0                 // NSLICE*792 partials: [s][k(0..9)*72 + j*3+c], [s][720 + j*3+c]
#define WS_SJF 6336              // 792 summed: SJ[k][j*3+c] (720), JT[j*3+c] (72)
#define WS_PFT 7168              // pose_feature TRANSPOSED [k(207)][b(1024)]
#define WS_A   219136            // A'[b][j][16]  (1024*384)

// ---------------------------------------------------------------------------
// K0: partial reductions of SJ/JT over vertex slices.
// grid: (24 joints, NSLICE), 256 threads
// ---------------------------------------------------------------------------
__global__ __launch_bounds__(256) void k0_joint_reduce(
    const float* __restrict__ v_template,
    const float* __restrict__ shapedirs,
    const float* __restrict__ J_regressor,
    float* __restrict__ ws)
{
    int j = blockIdx.x;
    int s = blockIdx.y;
    int t = threadIdx.x;
    int lane = t & 63, wid = t >> 6;
    int v0 = s * SLICE_V;
    int v1 = v0 + SLICE_V; if (v1 > NVERT) v1 = NVERT;

    float acc[33];   // [k][c] for k<10 shapedirs; 30..32 = v_template
#pragma unroll
    for (int i = 0; i < 33; ++i) acc[i] = 0.f;

    for (int v = v0 + t; v < v1; v += 256) {
        float jr = J_regressor[v * 24 + j];
        const float* vp = v_template + v * 3;
        acc[30] = fmaf(vp[0], jr, acc[30]);
        acc[31] = fmaf(vp[1], jr, acc[31]);
        acc[32] = fmaf(vp[2], jr, acc[32]);
#pragma unroll
        for (int k = 0; k < 10; ++k) {
            const float* p = shapedirs + k * V3 + v * 3;
            acc[k * 3 + 0] = fmaf(p[0], jr, acc[k * 3 + 0]);
            acc[k * 3 + 1] = fmaf(p[1], jr, acc[k * 3 + 1]);
            acc[k * 3 + 2] = fmaf(p[2], jr, acc[k * 3 + 2]);
        }
    }

    // wave-level butterfly reduce
#pragma unroll
    for (int i = 0; i < 33; ++i) {
#pragma unroll
        for (int o = 32; o > 0; o >>= 1)
            acc[i] += __shfl_xor(acc[i], o, 64);
    }

    __shared__ float part[4][33];
    if (lane == 0) {
#pragma unroll
        for (int i = 0; i < 33; ++i) part[wid][i] = acc[i];
    }
    __syncthreads();
    if (t < 33) {
        float r = part[0][t] + part[1][t] + part[2][t] + part[3][t];
        int k = t / 3, c = t % 3;
        int off = (k < 10) ? (WS_SJP + s * 792 + k * 72 + j * 3 + c)
                           : (WS_SJP + s * 792 + 720 + j * 3 + c);
        ws[off] = r;
    }
}

// K0b: sum slice partials -> final SJ/JT
__global__ __launch_bounds__(256) void k0b_sum(float* __restrict__ ws)
{
    int i = blockIdx.x * 256 + threadIdx.x;
    if (i < 792) {
        float r = 0.f;
#pragma unroll
        for (int s = 0; s < NSLICE; ++s) r += ws[WS_SJP + s * 792 + i];
        ws[WS_SJF + i] = r;
    }
}

// ---------------------------------------------------------------------------
// K1: per-batch Rodrigues + J + transposed pose_feature + kinematic chain.
// grid: 256 blocks x 256 threads (4 waves, wave = 1 batch)
// ---------------------------------------------------------------------------
__global__ __launch_bounds__(256) void k1_pose(
    const float* __restrict__ theta,
    const float* __restrict__ beta,
    float* __restrict__ ws)
{
    int t = threadIdx.x;
    int lane = t & 63, wid = t >> 6;
    int b = blockIdx.x * 4 + wid;

    __shared__ float Rs[4][24][9];
    __shared__ float Jl[4][24][3];
    __shared__ float res[4][24][16];
    __shared__ float Ai[4][16];

    if (lane < 24) {
        float tx = theta[b * 72 + lane * 3 + 0];
        float ty = theta[b * 72 + lane * 3 + 1];
        float tz = theta[b * 72 + lane * 3 + 2];
        float ax = tx + 1e-8f, ay = ty + 1e-8f, az = tz + 1e-8f;
        float ang = sqrtf(ax * ax + ay * ay + az * az);
        float h = 0.5f * ang;
        float cw = cosf(h), sw = sinf(h);
        float qw = cw;
        float qx = sw * (tx / ang);
        float qy = sw * (ty / ang);
        float qz = sw * (tz / ang);
        float qn = sqrtf(qw * qw + qx * qx + qy * qy + qz * qz);
        qw /= qn; qx /= qn; qy /= qn; qz /= qn;
        float w2 = qw * qw, x2 = qx * qx, y2 = qy * qy, z2 = qz * qz;
        float wx = qw * qx, wy = qw * qy, wz = qw * qz;
        float xy = qx * qy, xz = qx * qz, yz = qy * qz;
        Rs[wid][lane][0] = w2 + x2 - y2 - z2;
        Rs[wid][lane][1] = 2.f * xy - 2.f * wz;
        Rs[wid][lane][2] = 2.f * wy + 2.f * xz;
        Rs[wid][lane][3] = 2.f * wz + 2.f * xy;
        Rs[wid][lane][4] = w2 - x2 + y2 - z2;
        Rs[wid][lane][5] = 2.f * yz - 2.f * wx;
        Rs[wid][lane][6] = 2.f * xz - 2.f * wy;
        Rs[wid][lane][7] = 2.f * wx + 2.f * yz;
        Rs[wid][lane][8] = w2 - x2 - y2 + z2;
    }

    // J[j][c] = JT + sum_k beta[k]*SJ[k]
    for (int i = lane; i < 72; i += 64) {
        float sacc = ws[WS_SJF + 720 + i];
#pragma unroll
        for (int k = 0; k < 10; ++k)
            sacc = fmaf(beta[b * 10 + k], ws[WS_SJF + k * 72 + i], sacc);
        Jl[wid][i / 3][i % 3] = sacc;
    }
    __syncthreads();

    // pose_feature transposed: ws[WS_PFT + i*1024 + b]
    for (int i = lane; i < 207; i += 64) {
        int jj = 1 + i / 9, e = i % 9;
        float sub = (e == 0 || e == 4 || e == 8) ? 1.f : 0.f;
        ws[WS_PFT + i * NBATCH + b] = Rs[wid][jj][e] - sub;
    }

    if (lane < 16) {
        int r = lane >> 2, c = lane & 3;
        res[wid][0][lane] = (r < 3) ? (c < 3 ? Rs[wid][0][r * 3 + c] : Jl[wid][0][r])
                                    : (c == 3 ? 1.f : 0.f);
    }
    __syncthreads();

    const int PAR[24] = {-1,0,0,0,1,2,3,4,5,6,7,8,9,9,9,12,13,14,16,17,18,19,20,21};
#pragma unroll
    for (int i = 1; i < 24; ++i) {
        int p = PAR[i];
        if (lane < 16) {
            int r = lane >> 2, c = lane & 3;
            Ai[wid][lane] = (r < 3) ? (c < 3 ? Rs[wid][i][r * 3 + c]
                                             : (Jl[wid][i][r] - Jl[wid][p][r]))
                                    : (c == 3 ? 1.f : 0.f);
        }
        __syncthreads();
        if (lane < 16) {
            int r = lane >> 2, c = lane & 3;
            float sacc = 0.f;
#pragma unroll
            for (int k = 0; k < 4; ++k)
                sacc = fmaf(res[wid][p][r * 4 + k], Ai[wid][k * 4 + c], sacc);
            res[wid][i][lane] = sacc;
        }
        __syncthreads();
    }

    for (int i = lane; i < 384; i += 64) {
        int jj = i >> 4, rc = i & 15, r = rc >> 2, cc = rc & 3;
        float val = res[wid][jj][rc];
        if (cc == 3 && r < 3) {
            val -= res[wid][jj][r * 4 + 0] * Jl[wid][jj][0]
                 + res[wid][jj][r * 4 + 1] * Jl[wid][jj][1]
                 + res[wid][jj][r * 4 + 2] * Jl[wid][jj][2];
        }
        ws[WS_A + b * 384 + i] = val;
    }
}

// ---------------------------------------------------------------------------
// K2: vertex kernel. ZERO LDS — all block-uniform operands via scalar loads.
// grid: (NBATCH/BT = 64, 27), 256 threads; 1 vertex/thread, BT batches.
// ---------------------------------------------------------------------------
__global__ __launch_bounds__(256) void k2_vertex(
    const float* __restrict__ beta,
    const float* __restrict__ v_template,
    const float* __restrict__ shapedirs,
    const float* __restrict__ posedirs,
    const float* __restrict__ weights,
    const float* __restrict__ ws,
    float* __restrict__ out)
{
    int t  = threadIdx.x;
    int bg = blockIdx.x;            // batch group (x-major so same-vb blocks are consecutive)
    int vb = blockIdx.y;
    int v  = vb * 256 + t;
    bool valid = v < NVERT;
    int vc = valid ? v : (NVERT - 1);

    float a0[BT], a1[BT], a2[BT];
    {
        const float* vp = v_template + vc * 3;
        float t0 = vp[0], t1 = vp[1], t2 = vp[2];
#pragma unroll
        for (int bt = 0; bt < BT; ++bt) { a0[bt] = t0; a1[bt] = t1; a2[bt] = t2; }
    }

    // shapedirs (K=10), beta via uniform (scalar) loads
#pragma unroll
    for (int k = 0; k < 10; ++k) {
        const float* p = shapedirs + k * V3 + vc * 3;
        float s0 = p[0], s1 = p[1], s2 = p[2];
        const float* bb = beta + bg * BT * 10 + k;
#pragma unroll
        for (int bt = 0; bt < BT; ++bt) {
            float f = bb[bt * 10];
            a0[bt] = fmaf(f, s0, a0[bt]);
            a1[bt] = fmaf(f, s1, a1[bt]);
            a2[bt] = fmaf(f, s2, a2[bt]);
        }
    }

    // posedirs (K=207), pose_feature via uniform loads of transposed layout
    const float* pfb = ws + WS_PFT + bg * BT;
#pragma unroll 2
    for (int k = 0; k < 207; ++k) {
        const float* p = posedirs + k * V3 + vc * 3;
        float s0 = p[0], s1 = p[1], s2 = p[2];
        const float* pk = pfb + k * NBATCH;
#pragma unroll
        for (int bt = 0; bt < BT; ++bt) {
            float f = pk[bt];
            a0[bt] = fmaf(f, s0, a0[bt]);
            a1[bt] = fmaf(f, s1, a1[bt]);
            a2[bt] = fmaf(f, s2, a2[bt]);
        }
    }

    // skinning weights (per-thread, statically indexed below)
    float w[24];
#pragma unroll
    for (int j = 0; j < 24; ++j) w[j] = weights[vc * 24 + j];

    // skinning: M_bt = sum_j w_j * A_j  (A via uniform scalar loads), then o = M.p
    const float* Ab = ws + WS_A + (size_t)bg * BT * 384;
#pragma unroll
    for (int bt = 0; bt < BT; ++bt) {
        float M[12];
#pragma unroll
        for (int e = 0; e < 12; ++e) M[e] = 0.f;
#pragma unroll
        for (int j = 0; j < 24; ++j) {
            const float* Aj = Ab + bt * 384 + j * 16;
            float wj = w[j];
#pragma unroll
            for (int e = 0; e < 12; ++e)
                M[e] = fmaf(wj, Aj[e], M[e]);
        }
        float x = a0[bt], y = a1[bt], z = a2[bt];
        float o0 = fmaf(M[0], x, fmaf(M[1], y, fmaf(M[2],  z, M[3])));
        float o1 = fmaf(M[4], x, fmaf(M[5], y, fmaf(M[6],  z, M[7])));
        float o2 = fmaf(M[8], x, fmaf(M[9], y, fmaf(M[10], z, M[11])));
        if (valid) {
            float* po = out + (size_t)(bg * BT + bt) * V3 + v * 3;
            po[0] = o0; po[1] = o1; po[2] = o2;
        }
    }
}

extern "C" void kernel_launch(void* const* d_in, const int* in_sizes, int n_in,
                              void* d_out, int out_size, void* d_ws, size_t ws_size,
                              hipStream_t stream) {
    const float* theta       = (const float*)d_in[0];
    const float* beta        = (const float*)d_in[1];
    const float* v_template  = (const float*)d_in[2];
    const float* shapedirs   = (const float*)d_in[3];
    const float* posedirs    = (const float*)d_in[4];
    const float* J_regressor = (const float*)d_in[5];
    const float* weights     = (const float*)d_in[6];
    float* out = (float*)d_out;
    float* ws  = (float*)d_ws;

    hipLaunchKernelGGL(k0_joint_reduce, dim3(24, NSLICE), dim3(256), 0, stream,
                       v_template, shapedirs, J_regressor, ws);
    hipLaunchKernelGGL(k0b_sum, dim3(4), dim3(256), 0, stream, ws);
    hipLaunchKernelGGL(k1_pose, dim3(NBATCH / 4), dim3(256), 0, stream,
                       theta, beta, ws);
    hipLaunchKernelGGL(k2_vertex, dim3(NBATCH / BT, (NVERT + 255) / 256), dim3(256), 0, stream,
                       beta, v_template, shapedirs, posedirs, weights, ws, out);
}